// Round 7
// baseline (18.539 us; speedup 1.0000x reference)
//
#include <hip/hip_runtime.h>

// out[b][s][d] = W[d][s] + bias[d], b<4, s<4096, d<1024
// W: [1024][8192] fp32 row-major; out: [4][4096][1024] fp32.
//
// R7: isolate READ-segment length. TS=128 -> each W-row read is 512 B
// (vs 128 B in R3), 4x better DRAM page/channel locality on the 32 KB-
// strided read stream. Writes stay 256 B fragments (R5: insensitive).
// Per-thread instruction counts identical to R3; only the tile aspect
// ratio changes. LDS tile[64][129]: store-phase column read = 2-way
// bank alias (free, m136); load-phase scatter write 4-way (16 MB total,
// negligible).
// History: NT -19% (R2); occupancy neutral (R3); batch-in-grid read amp
// +59% (R4); 1KB write fragments neutral (R5); reg-pipelining neutral (R6).

constexpr int S = 4096;
constexpr int D = 1024;
constexpr int MAXLEN = 8192;
constexpr int BATCH = 4;
constexpr int TS = 128;           // s-cols per tile (512 B read segment per W row)
constexpr int TD = 64;            // d-rows per tile (256 B write fragment)
constexpr int PAD = 1;            // LDS row stride 129 floats
constexpr int NTS = S / TS;       // 32
constexpr int NTD = D / TD;       // 16

__global__ __launch_bounds__(256)
void pos_emb_kernel(const float* __restrict__ W,
                    const float* __restrict__ bias,
                    float* __restrict__ out)
{
    __shared__ float tile[TD][TS + PAD];   // 33 KB: tile[dl][sl] = W[d0+dl][s0+sl]

    const int ts = blockIdx.x % NTS;
    const int td = blockIdx.x / NTS;
    const int s0 = ts * TS;
    const int d0 = td * TD;
    const int tid = threadIdx.x;

    // ---- Load: 64 rows x 512 B contiguous; lanes along s ----
    // 32 float4 per row; 8 rows per pass; 8 passes.
    {
        const int c  = tid & 31;   // float4 index within the s-row
        const int r0 = tid >> 5;   // row base 0..7
        #pragma unroll
        for (int p = 0; p < 8; ++p) {
            const int dl = r0 + p * 8;
            const float4 v = *reinterpret_cast<const float4*>(
                &W[(size_t)(d0 + dl) * MAXLEN + s0 + c * 4]);
            tile[dl][c * 4 + 0] = v.x;
            tile[dl][c * 4 + 1] = v.y;
            tile[dl][c * 4 + 2] = v.z;
            tile[dl][c * 4 + 3] = v.w;
        }
    }
    __syncthreads();

    // ---- Store: 128 s-rows x 256 B fragments, x4 batches ----
    // 16 float4 along d; 16 s-rows per pass; 8 passes.
    {
        const int cd = tid & 15;   // float4 index along d (16 per row)
        const int rs = tid >> 4;   // s-row base 0..15
        const float4 bv = *reinterpret_cast<const float4*>(&bias[d0 + cd * 4]);
        #pragma unroll
        for (int i = 0; i < 8; ++i) {
            const int sl = rs + i * 16;
            float4 v;
            v.x = tile[cd * 4 + 0][sl] + bv.x;
            v.y = tile[cd * 4 + 1][sl] + bv.y;
            v.z = tile[cd * 4 + 2][sl] + bv.z;
            v.w = tile[cd * 4 + 3][sl] + bv.w;
            const size_t base = (size_t)(s0 + sl) * D + d0 + cd * 4;
            #pragma unroll
            for (int b = 0; b < BATCH; ++b) {
                *reinterpret_cast<float4*>(&out[base + (size_t)b * S * D]) = v;
            }
        }
    }
}

extern "C" void kernel_launch(void* const* d_in, const int* in_sizes, int n_in,
                              void* d_out, int out_size, void* d_ws, size_t ws_size,
                              hipStream_t stream) {
    // setup_inputs order: x (unused), W, b
    const float* W    = (const float*)d_in[1];
    const float* bias = (const float*)d_in[2];
    float* out        = (float*)d_out;

    const int grid = NTS * NTD;            // 512 blocks, 256 threads
    pos_emb_kernel<<<grid, 256, 0, stream>>>(W, bias, out);
}